// Round 3
// baseline (550.075 us; speedup 1.0000x reference)
//
#include <hip/hip_runtime.h>

#define S 16
#define B 8
#define H 16
#define DH 64
#define D 1024
#define HD 1024          // H*DH
#define LC 8192
#define LMAX (LC + S)    // 8208
#define NCH 16           // L-chunks per (b,h)
#define CHT 512          // t rows per chunk
#define ST 64            // subtile rows staged in LDS
#define KPAD 68          // padded row length (floats)

// ---- QKV projection: 4 rows/block, scalar-uniform x loads, coalesced W ----
// grid = 32 rowgroups * 12 (mat,chunk); block = 256
__global__ __launch_bounds__(256) void proj_qkv(const float* __restrict__ x,
        const float* __restrict__ Wq, const float* __restrict__ Wk,
        const float* __restrict__ Wv,
        float* __restrict__ q_ws, float* __restrict__ newk, float* __restrict__ newv)
{
    int bx = blockIdx.x;
    int rg  = bx / 12;
    int rem = bx % 12;
    int mat = rem >> 2, chunk = rem & 3;
    int o = chunk * 256 + threadIdx.x;
    const float* W  = (mat == 0) ? Wq : ((mat == 1) ? Wk : Wv);
    const float* xr = x + (size_t)rg * 4 * D;

    float a0 = 0.f, a1 = 0.f, a2 = 0.f, a3 = 0.f;
    #pragma unroll 8
    for (int d = 0; d < D; ++d) {
        float w = W[(size_t)d * HD + o];       // coalesced, L2-resident after 1st pass
        a0 += xr[d] * w;                       // uniform -> s_load
        a1 += xr[D + d] * w;
        a2 += xr[2 * D + d] * w;
        a3 += xr[3 * D + d] * w;
    }
    float acc[4] = {a0, a1, a2, a3};
    #pragma unroll
    for (int i = 0; i < 4; ++i) {
        int row = rg * 4 + i;
        int s = row >> 3, b = row & 7;
        if (mat == 0) {
            q_ws[(size_t)row * HD + o] = acc[i];
        } else {
            float* dst = (mat == 1) ? newk : newv;
            dst[(size_t)((LC + s) * B + b) * HD + o] = acc[i];
        }
    }
}

// ---- fused cache-copy + flash attention, register-prefetch pipelined ------
// grid = B*H*NCH (bh*16 + chunk), block = 256 (4 waves; wave sg owns s in [4sg,4sg+4))
__global__ __launch_bounds__(256) void attn_fused(const float* __restrict__ q_ws,
        const float* __restrict__ cache_k, const float* __restrict__ cache_v,
        float* __restrict__ newk, float* __restrict__ newv,
        float* __restrict__ m_part, float* __restrict__ l_part,
        float* __restrict__ pv_part)
{
    __shared__ float Ks[ST][KPAD];
    __shared__ float Vs[ST][KPAD];
    __shared__ float qs[S][KPAD];
    __shared__ float sc[S][ST];

    int chunk = blockIdx.x & 15;
    int bh    = blockIdx.x >> 4;
    int h = bh & 15, b = bh >> 4;
    int tid = threadIdx.x, lane = tid & 63, sg = tid >> 6;
    int r = tid >> 4, c = tid & 15;

    // q tile (16x64) into LDS (covered by first barrier)
    *(float4*)&qs[r][c * 4] =
        *(const float4*)(q_ws + ((size_t)(r * B + b)) * HD + h * DH + c * 4);

    float m_prev[4], l_acc[4], pv_acc[4];
    #pragma unroll
    for (int j = 0; j < 4; ++j) { m_prev[j] = -1e30f; l_acc[j] = 0.f; pv_acc[j] = 0.f; }

    // scores + online softmax + PV over the staged tile
    auto compute_tile = [&](int t0, int nrows) {
        float a0 = 0.f, a1 = 0.f, a2 = 0.f, a3 = 0.f;
        #pragma unroll
        for (int i = 0; i < 16; ++i) {
            float4 k4 = *(float4*)&Ks[lane][i * 4];
            float4 q0 = *(float4*)&qs[sg * 4 + 0][i * 4];
            float4 q1 = *(float4*)&qs[sg * 4 + 1][i * 4];
            float4 q2 = *(float4*)&qs[sg * 4 + 2][i * 4];
            float4 q3 = *(float4*)&qs[sg * 4 + 3][i * 4];
            a0 += k4.x * q0.x + k4.y * q0.y + k4.z * q0.z + k4.w * q0.w;
            a1 += k4.x * q1.x + k4.y * q1.y + k4.z * q1.z + k4.w * q1.w;
            a2 += k4.x * q2.x + k4.y * q2.y + k4.z * q2.z + k4.w * q2.w;
            a3 += k4.x * q3.x + k4.y * q3.y + k4.z * q3.z + k4.w * q3.w;
        }
        float a[4] = { a0 * 0.125f, a1 * 0.125f, a2 * 0.125f, a3 * 0.125f };

        int tg = t0 + lane;
        #pragma unroll
        for (int j = 0; j < 4; ++j) {
            int s = sg * 4 + j;
            if (lane >= nrows || tg > LC + s) a[j] = -1e30f;
        }

        float scale_f[4];
        #pragma unroll
        for (int j = 0; j < 4; ++j) {
            float v = a[j];
            #pragma unroll
            for (int msk = 32; msk; msk >>= 1) v = fmaxf(v, __shfl_xor(v, msk));
            float mn = fmaxf(m_prev[j], v);
            scale_f[j] = __expf(m_prev[j] - mn);
            m_prev[j] = mn;
            sc[sg * 4 + j][lane] = __expf(a[j] - mn);
        }
        // own-wave sc writes -> own-wave sc reads: same-wave DS ordering + fence
        asm volatile("s_waitcnt lgkmcnt(0)" ::: "memory");

        #pragma unroll
        for (int j = 0; j < 4; ++j) { l_acc[j] *= scale_f[j]; pv_acc[j] *= scale_f[j]; }
        for (int tt = 0; tt < 16; ++tt) {
            float v0 = Vs[tt * 4 + 0][lane];
            float v1 = Vs[tt * 4 + 1][lane];
            float v2 = Vs[tt * 4 + 2][lane];
            float v3 = Vs[tt * 4 + 3][lane];
            #pragma unroll
            for (int j = 0; j < 4; ++j) {
                float4 p = *(float4*)&sc[sg * 4 + j][tt * 4];
                pv_acc[j] += p.x * v0 + p.y * v1 + p.z * v2 + p.w * v3;
                l_acc[j]  += p.x + p.y + p.z + p.w;
            }
        }
    };

    int t0base = chunk * CHT;

    // prefetch subtile 0 into register buffer 0
    float4 kr[2][4], vr[2][4];
    #pragma unroll
    for (int g = 0; g < 4; ++g) {
        size_t off = ((size_t)(t0base + r + 16 * g) * B + b) * HD + h * DH + c * 4;
        kr[0][g] = *(const float4*)(cache_k + off);
        vr[0][g] = *(const float4*)(cache_v + off);
    }

    #pragma unroll
    for (int it = 0; it < 8; ++it) {   // full unroll: kr[cur] indices fold to constants
        const int cur = it & 1, nxt = cur ^ 1;
        int t0 = t0base + it * ST;

        __syncthreads();   // prev subtile's LDS readers done (also waits cur prefetch data)

        #pragma unroll
        for (int g = 0; g < 4; ++g) {
            size_t off = ((size_t)(t0 + r + 16 * g) * B + b) * HD + h * DH + c * 4;
            *(float4*)&Ks[r + 16 * g][c * 4] = kr[cur][g];
            *(float4*)&Vs[r + 16 * g][c * 4] = vr[cur][g];
            *(float4*)(newk + off) = kr[cur][g];   // the cache copy
            *(float4*)(newv + off) = vr[cur][g];
        }
        if (it + 1 < 8) {   // issue next prefetch; stays in flight across the barrier
            #pragma unroll
            for (int g = 0; g < 4; ++g) {
                size_t off = ((size_t)(t0 + ST + r + 16 * g) * B + b) * HD + h * DH + c * 4;
                kr[nxt][g] = *(const float4*)(cache_k + off);
                vr[nxt][g] = *(const float4*)(cache_v + off);
            }
        }
        // counted-wait barrier: only LDS must be visible; do NOT drain vmcnt
        asm volatile("s_waitcnt lgkmcnt(0)" ::: "memory");
        __builtin_amdgcn_s_barrier();
        asm volatile("" ::: "memory");

        compute_tile(t0, ST);
    }

    if (chunk == NCH - 1) {   // tail: 16 new rows, already in newk/newv from proj_qkv
        __syncthreads();
        {
            size_t off = ((size_t)(LC + r) * B + b) * HD + h * DH + c * 4;
            *(float4*)&Ks[r][c * 4] = *(const float4*)(newk + off);
            *(float4*)&Vs[r][c * 4] = *(const float4*)(newv + off);
        }
        asm volatile("s_waitcnt lgkmcnt(0)" ::: "memory");
        __builtin_amdgcn_s_barrier();
        asm volatile("" ::: "memory");
        compute_tile(LC, S);
    }

    int pi = blockIdx.x;
    #pragma unroll
    for (int j = 0; j < 4; ++j) {
        int s = sg * 4 + j;
        pv_part[((size_t)pi * S + s) * DH + lane] = pv_acc[j];
        if (lane == 0) {
            m_part[pi * S + s] = m_prev[j];
            l_part[pi * S + s] = l_acc[j];
        }
    }
}

// ---- combine partials over chunks -> ctx ----------------------------------
__global__ __launch_bounds__(64) void combine(const float* __restrict__ m_part,
        const float* __restrict__ l_part, const float* __restrict__ pv_part,
        float* __restrict__ ctx)
{
    int s  = blockIdx.x & 15;
    int bh = blockIdx.x >> 4;
    int h = bh & 15, b = bh >> 4;
    int d = threadIdx.x;

    float M = -1e30f;
    #pragma unroll
    for (int cc = 0; cc < NCH; ++cc) M = fmaxf(M, m_part[(bh * NCH + cc) * S + s]);
    float L = 0.f, acc = 0.f;
    #pragma unroll
    for (int cc = 0; cc < NCH; ++cc) {
        int pi = bh * NCH + cc;
        float w = __expf(m_part[pi * S + s] - M);
        L   += l_part[pi * S + s] * w;
        acc += w * pv_part[((size_t)pi * S + s) * DH + d];
    }
    ctx[((size_t)(s * B + b)) * HD + h * DH + d] = acc / L;
}

// ---- output projection: 2 rows/block, scalar-uniform ctx loads ------------
// grid = 64 rowgroups * 4 chunks; block = 256
__global__ __launch_bounds__(256) void proj_o(const float* __restrict__ ctx,
                                              const float* __restrict__ Wo,
                                              float* __restrict__ res)
{
    int bx = blockIdx.x;
    int rg = bx >> 2, chunk = bx & 3;
    int o = chunk * 256 + threadIdx.x;
    const float* cr = ctx + (size_t)rg * 2 * HD;

    float a0 = 0.f, a1 = 0.f;
    #pragma unroll 8
    for (int d = 0; d < HD; ++d) {
        float w = Wo[(size_t)d * D + o];
        a0 += cr[d] * w;
        a1 += cr[HD + d] * w;
    }
    res[(size_t)(rg * 2) * D + o]     = a0;
    res[(size_t)(rg * 2 + 1) * D + o] = a1;
}

extern "C" void kernel_launch(void* const* d_in, const int* in_sizes, int n_in,
                              void* d_out, int out_size, void* d_ws, size_t ws_size,
                              hipStream_t stream)
{
    const float* x  = (const float*)d_in[0];
    const float* ck = (const float*)d_in[1];
    const float* cv = (const float*)d_in[2];
    const float* Wq = (const float*)d_in[3];
    const float* Wk = (const float*)d_in[4];
    const float* Wv = (const float*)d_in[5];
    const float* Wo = (const float*)d_in[6];

    float* out  = (float*)d_out;
    float* res  = out;                                   // (S,B,D)
    float* newk = out + (size_t)S * B * D;               // (L,B,H,DH)
    float* newv = newk + (size_t)LMAX * B * H * DH;

    float* q_ws    = (float*)d_ws;                            // S*B*HD
    float* ctx     = q_ws + (size_t)S * B * HD;
    float* m_part  = ctx + (size_t)S * B * HD;
    float* l_part  = m_part + (size_t)B * H * NCH * S;
    float* pv_part = l_part + (size_t)B * H * NCH * S;

    hipLaunchKernelGGL(proj_qkv, dim3(32 * 12), dim3(256), 0, stream,
                       x, Wq, Wk, Wv, q_ws, newk, newv);
    hipLaunchKernelGGL(attn_fused, dim3(B * H * NCH), dim3(256), 0, stream,
                       q_ws, ck, cv, newk, newv, m_part, l_part, pv_part);
    hipLaunchKernelGGL(combine, dim3(B * H * S), dim3(64), 0, stream,
                       m_part, l_part, pv_part, ctx);
    hipLaunchKernelGGL(proj_o, dim3(64 * 4), dim3(256), 0, stream,
                       ctx, Wo, res);
}